// Round 9
// baseline (732.040 us; speedup 1.0000x reference)
//
#include <hip/hip_runtime.h>

static constexpr int   Bn      = 32;
static constexpr int   Tn      = 2000;
static constexpr int   Hn      = 512;
static constexpr int   Ln      = 256;     // max_label_len
static constexpr float kThresh = 0.95f;
static constexpr int   TCHUNK  = 40;
static constexpr int   NTCH    = Tn / TCHUNK;   // 50
static constexpr int   NPROD   = Bn;            // 32 producer blocks (first!)
static constexpr unsigned DONE = 1u << 16;
static constexpr int   FDSTRIDE = 16;           // pad fires_done to 64 B/row

// ---------------------------------------------------------------------------
// Fused producer-consumer kernel. Producers are blocks 0..31 (dispatched and
// scheduled FIRST -> no deadlock): per-row serial integrate-and-fire chain
// (bit-exact reference op order, register-only, double-buffered alpha
// prefetch). Fires are written to the table AS THEY HAPPEN (lane-0 stores,
// ~1 per 8 steps) and progress fires_done[b]=fc is published per chunk with
// an agent-scope RELEASE store (orders table stores before the counter).
// Consumers (one block per output slot (s,b)) spin with acquire loads +
// s_sleep until fc >= s+1 (their segment's boundaries are published) or
// DONE, then accumulate their segment from hidden and plain-store it --
// overlapping the bandwidth phase under the serial scan instead of after it.
// Zero-slots (s >= final fc) are written as zeros -> every output element is
// stored exactly once per call, no pre-zero pass, graph-replay safe.
// ---------------------------------------------------------------------------
__global__ __launch_bounds__(128) void cif_fused_kernel(
    const float* __restrict__ hidden,
    const float* __restrict__ alphas,
    unsigned* __restrict__ fires_done,  // [Bn*FDSTRIDE], slot b*FDSTRIDE
    int*      __restrict__ tf,          // [Bn][Ln] fire timestep
    float2*   __restrict__ cwrem,       // [Bn][Ln] (closing w, remainder w)
    float*    __restrict__ out) {
  if (blockIdx.x < NPROD) {
    // ---------------- producer: serial scan for row b ----------------
    if (threadIdx.x >= 64) return;      // one wave; no barriers used
    const int b    = blockIdx.x;
    const int lane = threadIdx.x;
    const float4* __restrict__ arow =
        reinterpret_cast<const float4*>(alphas + (size_t)b * Tn);
    constexpr int CV = TCHUNK / 4;      // 10 float4 per chunk

    float integrate = 0.0f;
    int   fc        = 0;

    float4 cur[CV], nxt[CV];
#pragma unroll
    for (int i = 0; i < CV; ++i) cur[i] = arow[i];

    for (int c = 0; c < NTCH; ++c) {
      if (c + 1 < NTCH) {
#pragma unroll
        for (int i = 0; i < CV; ++i) nxt[i] = arow[(c + 1) * CV + i];
      }
      const int tbase = c * TCHUNK;
#pragma unroll
      for (int i = 0; i < CV; ++i) {
        const float a4[4] = {cur[i].x, cur[i].y, cur[i].z, cur[i].w};
#pragma unroll
        for (int j = 0; j < 4; ++j) {
          const float a     = a4[j];
          const float integ = integrate + a;      // reference op order
          const bool  fire  = integ > kThresh;
          if (fire && lane == 0 && fc < Ln) {     // rare (~1/8 steps)
            const float cw = 1.0f - integrate;    // dist_completion
            tf   [b * Ln + fc] = tbase + i * 4 + j;
            cwrem[b * Ln + fc] = make_float2(cw, a - cw);
          }
          integrate = fire ? (integ - 1.0f) : integ;  // keep select form
          fc += fire ? 1 : 0;                         // (proven chain)
        }
      }
#pragma unroll
      for (int i = 0; i < CV; ++i) cur[i] = nxt[i];
      if (lane == 0)   // release: table stores visible before counter bump
        __hip_atomic_store(&fires_done[b * FDSTRIDE], (unsigned)fc,
                           __ATOMIC_RELEASE, __HIP_MEMORY_SCOPE_AGENT);
    }
    if (lane == 0)
      __hip_atomic_store(&fires_done[b * FDSTRIDE], (unsigned)fc | DONE,
                         __ATOMIC_RELEASE, __HIP_MEMORY_SCOPE_AGENT);
    return;
  }

  // ---------------- consumer: output slot (s, b) ----------------
  const int c   = blockIdx.x - NPROD;
  const int b   = c & (Bn - 1);        // consecutive blocks spread over rows
  const int s   = c >> 5;              // 0..Ln-1; low s dispatched first
  const int col = threadIdx.x * 4;

  __shared__ unsigned s_v;
  if (threadIdx.x == 0) {
    unsigned v;
    for (;;) {
      v = __hip_atomic_load(&fires_done[b * FDSTRIDE], __ATOMIC_ACQUIRE,
                            __HIP_MEMORY_SCOPE_AGENT);
      if ((v & 0xFFFFu) >= (unsigned)(s + 1) || (v & DONE)) break;
      __builtin_amdgcn_s_sleep(16);
    }
    s_v = v;
  }
  __syncthreads();
  const int fc_now = (int)(s_v & 0xFFFFu);

  float* __restrict__ o = out + ((size_t)b * Ln + s) * Hn + col;

  if (fc_now < s + 1) {                // DONE and slot never fires: zeros
    *reinterpret_cast<float4*>(o) = make_float4(0.f, 0.f, 0.f, 0.f);
    return;
  }

  // Fired slot: segment (t_prev, t_hi], reference accumulation order.
  const int t_hi   = tf[b * Ln + s];
  const int t_prev = (s > 0) ? tf[b * Ln + s - 1] : -1;

  const float* __restrict__ hbase = hidden + (size_t)b * Tn * Hn + col;
  const float* __restrict__ arow  = alphas + (size_t)b * Tn;

  float4 acc = make_float4(0.f, 0.f, 0.f, 0.f);

  if (s > 0) {                         // opening: frame = rem * h[t_prev]
    const float r  = cwrem[b * Ln + s - 1].y;
    const float4 h = *reinterpret_cast<const float4*>(hbase + (size_t)t_prev * Hn);
    acc.x = r * h.x; acc.y = r * h.y; acc.z = r * h.z; acc.w = r * h.w;
  }
  for (int t = t_prev + 1; t < t_hi; ++t) {   // interior: weight = raw alpha
    const float a  = arow[t];
    const float4 h = *reinterpret_cast<const float4*>(hbase + (size_t)t * Hn);
    acc.x += a * h.x; acc.y += a * h.y; acc.z += a * h.z; acc.w += a * h.w;
  }
  {                                    // closing: weight = dist_completion
    const float cw = cwrem[b * Ln + s].x;
    const float4 h = *reinterpret_cast<const float4*>(hbase + (size_t)t_hi * Hn);
    acc.x += cw * h.x; acc.y += cw * h.y; acc.z += cw * h.z; acc.w += cw * h.w;
  }
  *reinterpret_cast<float4*>(o) = acc;
}

extern "C" void kernel_launch(void* const* d_in, const int* in_sizes, int n_in,
                              void* d_out, int out_size, void* d_ws, size_t ws_size,
                              hipStream_t stream) {
  const float* hidden = (const float*)d_in[0];
  const float* alphas = (const float*)d_in[1];
  float* out = (float*)d_out;

  // ws layout: fires_done[Bn*FDSTRIDE] u32 (2 KB, memset each call)
  //          | tf[B][Ln] i32 (32 KB) | cwrem[B][Ln] float2 (64 KB)
  unsigned* fires_done = (unsigned*)d_ws;
  int*      tf         = (int*)(fires_done + (size_t)Bn * FDSTRIDE);
  float2*   cwrem      = (float2*)(tf + (size_t)Bn * Ln);

  // Progress flags must start at 0 every call (ws may be poisoned/stale).
  hipMemsetAsync(fires_done, 0, (size_t)Bn * FDSTRIDE * sizeof(unsigned),
                 stream);

  const int nblocks = NPROD + Bn * Ln;   // 32 producers + 8192 consumers
  cif_fused_kernel<<<nblocks, 128, 0, stream>>>(hidden, alphas, fires_done,
                                                tf, cwrem, out);
}

// Round 10
// 77.459 us; speedup vs baseline: 9.4507x; 9.4507x over previous
//
#include <hip/hip_runtime.h>

static constexpr int   Bn      = 32;
static constexpr int   Tn      = 2000;
static constexpr int   Hn      = 512;
static constexpr int   Ln      = 256;     // max_label_len
static constexpr float kThresh = 0.95f;
static constexpr int   TCHUNK  = 40;
static constexpr int   NTCH    = Tn / TCHUNK;   // 50

// ---------------------------------------------------------------------------
// K1: scan + fire-table build in ONE dispatch, one wave per batch row.
// __launch_bounds__(64, 1): min 1 wave/EU -> VGPR budget up to 256. R9's
// counters (VGPR_Count=12 on a kernel needing 80+ regs of alpha buffers)
// exposed that the default occupancy target has been SPILLING the
// double-buffer to scratch since R2 (R2: 92 regs for a 160-reg working set;
// R3: 48) -- scratch round-trips inside the serial loop are the missing
// ~35 us. One wave per CU on 32 CUs: occupancy 1 costs nothing here.
// Phase A (all 64 lanes redundantly): register-only serial recurrence,
// bit-exact reference op order; lane c captures chunk-c boundary state via
// predicated selects. Phase B (lanes 0..49): replay own chunk, emit fire
// table (t, cw, rem) per fire.
// ---------------------------------------------------------------------------
__global__ __launch_bounds__(64, 1) void cif_scan_table_kernel(
    const float* __restrict__ alphas,
    int*   __restrict__ tf,     // [Bn][Ln] fire timestep
    float* __restrict__ cwv,    // [Bn][Ln] closing weight (dist_completion)
    float* __restrict__ remv,   // [Bn][Ln] remainder weight (opens next seg)
    int*   __restrict__ fcnt) { // [Bn]
  const int b    = blockIdx.x;
  const int lane = threadIdx.x;
  const float4* __restrict__ arow =
      reinterpret_cast<const float4*>(alphas + (size_t)b * Tn);
  constexpr int CV = TCHUNK / 4;   // 10 float4 per chunk

  // ---- Phase A: serial scan, register-only ----
  float integrate = 0.0f;
  int   fc        = 0;
  float my_int    = 0.0f;          // lane `lane` snapshots chunk `lane`
  int   my_fc     = 0;

  float4 cur[CV], nxt[CV];
#pragma unroll
  for (int i = 0; i < CV; ++i) cur[i] = arow[i];

  for (int c = 0; c < NTCH; ++c) {
    if (c + 1 < NTCH) {
#pragma unroll
      for (int i = 0; i < CV; ++i) nxt[i] = arow[(c + 1) * CV + i];
    }
    const bool mine = (c == lane);
    my_int = mine ? integrate : my_int;
    my_fc  = mine ? fc        : my_fc;
#pragma unroll
    for (int i = 0; i < CV; ++i) {
      const float a4[4] = {cur[i].x, cur[i].y, cur[i].z, cur[i].w};
#pragma unroll
      for (int j = 0; j < 4; ++j) {
        const float integ = integrate + a4[j];    // reference op order
        const bool  fire  = integ > kThresh;
        integrate = fire ? (integ - 1.0f) : integ;
        fc += fire ? 1 : 0;
      }
    }
#pragma unroll
    for (int i = 0; i < CV; ++i) cur[i] = nxt[i];
  }
  if (lane == 0) fcnt[b] = fc;

  // ---- Phase B: per-lane chunk replay -> fire table ----
  if (lane < NTCH) {
    const int t0 = lane * TCHUNK;
    const float4* __restrict__ crow =
        reinterpret_cast<const float4*>(alphas + (size_t)b * Tn + t0);
    float av[TCHUNK];
#pragma unroll
    for (int i = 0; i < CV; ++i) {
      const float4 v = crow[i];
      av[4 * i + 0] = v.x; av[4 * i + 1] = v.y;
      av[4 * i + 2] = v.z; av[4 * i + 3] = v.w;
    }
    float ig = my_int;
    int   s  = my_fc;
#pragma unroll
    for (int k = 0; k < TCHUNK; ++k) {
      const float a     = av[k];
      const float integ = ig + a;                 // reference op order
      const bool  fire  = integ > kThresh;
      if (fire) {
        if (s < Ln) {
          const float cw  = 1.0f - ig;            // dist_completion
          const float rem = a - cw;               // remainds
          tf  [b * Ln + s] = t0 + k;
          cwv [b * Ln + s] = cw;
          remv[b * Ln + s] = rem;
        }
        s += 1;
        ig = integ - 1.0f;
      } else {
        ig = integ;
      }
    }
  }
}

// ---------------------------------------------------------------------------
// K2: per-segment accumulation — block (s, b) EXCLUSIVELY owns out[b][s].
// Segment s spans (t_prev, t_hi]: acc = rem[s-1]*h[t_prev] (replace-open)
// + sum of raw alpha_t * h_t over interior t + cw[s]*h[t_hi], accumulated
// ascending in t (reference order). Plain float4 stores, NO atomics; blocks
// with s >= min(fcnt,Ln) store zeros — so NO pre-zero pass is needed and
// every output element is written exactly once per call (graph-replay safe).
// ---------------------------------------------------------------------------
__global__ __launch_bounds__(128) void cif_seg_accum_kernel(
    const float* __restrict__ hidden,
    const float* __restrict__ alphas,
    const int*   __restrict__ tf,
    const float* __restrict__ cwv,
    const float* __restrict__ remv,
    const int*   __restrict__ fcnt,
    float* __restrict__ out) {
  const int s   = blockIdx.x;          // 0..Ln-1
  const int b   = blockIdx.y;          // 0..Bn-1
  const int col = threadIdx.x * 4;

  const int fb    = fcnt[b];
  const int limit = fb < Ln ? fb : Ln;

  float* __restrict__ o = out + ((size_t)b * Ln + s) * Hn + col;

  if (s >= limit) {                    // never-fired slot: emit zeros
    *reinterpret_cast<float4*>(o) = make_float4(0.f, 0.f, 0.f, 0.f);
    return;
  }

  const int t_hi   = tf[b * Ln + s];
  const int t_prev = (s > 0) ? tf[b * Ln + s - 1] : -1;

  const float* __restrict__ hbase = hidden + (size_t)b * Tn * Hn + col;
  const float* __restrict__ arow  = alphas + (size_t)b * Tn;

  float4 acc = make_float4(0.f, 0.f, 0.f, 0.f);

  if (s > 0) {                         // opening: frame = rem * h[t_prev]
    const float r  = remv[b * Ln + s - 1];
    const float4 h = *reinterpret_cast<const float4*>(hbase + (size_t)t_prev * Hn);
    acc.x = r * h.x; acc.y = r * h.y; acc.z = r * h.z; acc.w = r * h.w;
  }
  for (int t = t_prev + 1; t < t_hi; ++t) {   // interior: weight = raw alpha
    const float a  = arow[t];
    const float4 h = *reinterpret_cast<const float4*>(hbase + (size_t)t * Hn);
    acc.x += a * h.x; acc.y += a * h.y; acc.z += a * h.z; acc.w += a * h.w;
  }
  {                                    // closing: weight = dist_completion
    const float c  = cwv[b * Ln + s];
    const float4 h = *reinterpret_cast<const float4*>(hbase + (size_t)t_hi * Hn);
    acc.x += c * h.x; acc.y += c * h.y; acc.z += c * h.z; acc.w += c * h.w;
  }
  *reinterpret_cast<float4*>(o) = acc;
}

extern "C" void kernel_launch(void* const* d_in, const int* in_sizes, int n_in,
                              void* d_out, int out_size, void* d_ws, size_t ws_size,
                              hipStream_t stream) {
  const float* hidden = (const float*)d_in[0];
  const float* alphas = (const float*)d_in[1];
  float* out = (float*)d_out;

  // ws layout: tf[B][Ln] i32 (32 KB) | cw[B][Ln] f32 | rem[B][Ln] f32 | fcnt[B]
  int*   tf   = (int*)d_ws;
  float* cwv  = (float*)(tf + (size_t)Bn * Ln);
  float* remv = cwv + (size_t)Bn * Ln;
  int*   fcnt = (int*)(remv + (size_t)Bn * Ln);

  cif_scan_table_kernel<<<Bn, 64, 0, stream>>>(alphas, tf, cwv, remv, fcnt);

  dim3 grid(Ln, Bn);   // 8192 independent blocks, one per output slot
  cif_seg_accum_kernel<<<grid, 128, 0, stream>>>(hidden, alphas, tf, cwv,
                                                 remv, fcnt, out);
}